// Round 6
// baseline (921.095 us; speedup 1.0000x reference)
//
#include <hip/hip_runtime.h>
#include <stdint.h>
#include <math.h>

#define D_IN   1024
#define NQKV   3072
#define NHEADS 16
#define DH     64
#define BATCH  4
#define SEQ    2048
#define MTOT   (BATCH*SEQ)   // 8192

typedef __bf16    bf16x8 __attribute__((ext_vector_type(8)));
typedef _Float16  f16x8  __attribute__((ext_vector_type(8)));
typedef float     f32x4  __attribute__((ext_vector_type(4)));

typedef __attribute__((address_space(3))) unsigned short       lds_us;
typedef __attribute__((address_space(1))) const unsigned short glb_us;

__device__ __forceinline__ unsigned short f2bf(float f) {
    union { float f; uint32_t u; } c; c.f = f;
    uint32_t u = c.u;
    uint32_t r = u + 0x7fffu + ((u >> 16) & 1u);  // RNE
    return (unsigned short)(r >> 16);
}
__device__ __forceinline__ float bf2f(unsigned short b) {
    union { uint32_t u; float f; } c; c.u = ((uint32_t)b) << 16;
    return c.f;
}
__device__ __forceinline__ uint32_t pkh(float a, float b) {
    auto h = __builtin_amdgcn_cvt_pkrtz(a, b);   // __fp16 ext_vector(2)
    uint32_t u;
    __builtin_memcpy(&u, &h, 4);
    return u;
}

// ---------------- stage 0a: x fp32 -> bf16 ----------------
__global__ void k_convert_x(const float* __restrict__ x, unsigned short* __restrict__ xb) {
    int i = blockIdx.x * 256 + threadIdx.x;
    float4 v = ((const float4*)x)[i];
    ushort4 o;
    o.x = f2bf(v.x); o.y = f2bf(v.y); o.z = f2bf(v.z); o.w = f2bf(v.w);
    ((ushort4*)xb)[i] = o;
}

// ---------------- stage 0b: W fp32 [K][N] -> Wt bf16 [N][K] ----------------
__global__ void k_convert_wt(const float* __restrict__ W, unsigned short* __restrict__ Wt) {
    __shared__ float tile[32][33];
    int tx = threadIdx.x, ty = threadIdx.y;
    int n0 = blockIdx.x * 32, k0 = blockIdx.y * 32;
    #pragma unroll
    for (int i = 0; i < 4; ++i) {
        int k = k0 + ty + i*8;
        tile[ty + i*8][tx] = W[(size_t)k * NQKV + n0 + tx];
    }
    __syncthreads();
    #pragma unroll
    for (int i = 0; i < 4; ++i) {
        int n = n0 + ty + i*8;
        Wt[(size_t)n * D_IN + k0 + tx] = f2bf(tile[tx][ty + i*8]);
    }
}

// ---------------- stage 1: QKV = x @ W + b, m97-style global_load_lds GEMM ----------------
// 128x128 tile, BK=32, unpadded LDS [128][32] (2-way bank alias = free), DMA staging.
// Q columns (col%192 < 64) pre-scaled by 0.125*log2e so k_attn's exp2 needs no mul.
__global__ __launch_bounds__(256) void k_gemm_qkv(
    const unsigned short* __restrict__ A,   // [8192][1024] bf16
    const unsigned short* __restrict__ Bt,  // [3072][1024] bf16
    const float* __restrict__ bias,         // [3072]
    unsigned short* __restrict__ C)         // [8192][3072] bf16
{
    __shared__ __align__(16) unsigned short As[128*32];
    __shared__ __align__(16) unsigned short Bs[128*32];
    const int t = threadIdx.x;
    const int wave = t >> 6, lane = t & 63, quad = lane >> 4, l15 = lane & 15;
    const int wm = wave >> 1, wn = wave & 1;
    const int m0 = blockIdx.y * 128, n0 = blockIdx.x * 128;
    const int crow = lane >> 2;          // row within 16-row chunk
    const int ccol = (lane & 3) << 3;    // short col within row

    f32x4 acc[4][4] = {};
    lds_us* As3 = (lds_us*)As;
    lds_us* Bs3 = (lds_us*)Bs;

    for (int k0 = 0; k0 < D_IN; k0 += 32) {
        // stage A,B tiles: each wave DMAs 2 chunks of 16 rows each (1024 B per instr)
        #pragma unroll
        for (int j = 0; j < 2; ++j) {
            int chunk = wave*2 + j;
            const unsigned short* ga = A  + (size_t)(m0 + chunk*16 + crow)*D_IN + k0 + ccol;
            const unsigned short* gb = Bt + (size_t)(n0 + chunk*16 + crow)*D_IN + k0 + ccol;
            __builtin_amdgcn_global_load_lds((glb_us*)ga, As3 + chunk*512, 16, 0, 0);
            __builtin_amdgcn_global_load_lds((glb_us*)gb, Bs3 + chunk*512, 16, 0, 0);
        }
        __syncthreads();   // drains vmcnt -> staging visible
        bf16x8 a[4], b[4];
        #pragma unroll
        for (int tm = 0; tm < 4; ++tm)
            a[tm] = *(const bf16x8*)(&As[(wm*64 + tm*16 + l15)*32 + quad*8]);
        #pragma unroll
        for (int tn = 0; tn < 4; ++tn)
            b[tn] = *(const bf16x8*)(&Bs[(wn*64 + tn*16 + l15)*32 + quad*8]);
        #pragma unroll
        for (int tm = 0; tm < 4; ++tm)
            #pragma unroll
            for (int tn = 0; tn < 4; ++tn)
                acc[tm][tn] = __builtin_amdgcn_mfma_f32_16x16x32_bf16(a[tm], b[tn], acc[tm][tn], 0, 0, 0);
        __syncthreads();   // protect LDS before next iteration's DMA overwrite
    }
    const float qs = 0.125f * 1.44269504089f;
    #pragma unroll
    for (int tn = 0; tn < 4; ++tn) {
        int col = n0 + wn*64 + tn*16 + l15;
        float bv = bias[col];
        float s = ((col % 192) < 64) ? qs : 1.0f;   // pre-scale Q columns
        #pragma unroll
        for (int tm = 0; tm < 4; ++tm) {
            #pragma unroll
            for (int r = 0; r < 4; ++r) {
                int row = m0 + wm*64 + tm*16 + quad*4 + r;
                C[(size_t)row*NQKV + col] = f2bf((acc[tm][tn][r] + bv) * s);
            }
        }
    }
}

// ---------------- stage 1b: V (bf16, strided in qkv) -> Vt f16 [bh][d][s] ----------------
#define TP 66
__global__ __launch_bounds__(256) void k_transpose_v(
    const unsigned short* __restrict__ qkv,
    unsigned short* __restrict__ vtg)       // f16 bits
{
    __shared__ unsigned short T[64*TP];     // [s][d] as f16
    const int t = threadIdx.x;
    const int bh = blockIdx.y, b = bh >> 4, h = bh & 15;
    const int s0 = blockIdx.x * 64;
    const unsigned short* src = qkv + (size_t)(b*SEQ + s0)*NQKV + h*(3*DH) + 2*DH;
    #pragma unroll
    for (int i = 0; i < 2; ++i) {
        int idx = t + i*256;
        int s = idx >> 3, c = (idx & 7) << 3;
        uint4 v = *(const uint4*)(src + (size_t)s*NQKV + c);   // 16 B = 8 bf16
        unsigned short* dst = &T[s*TP + c];
        const unsigned short* pv = (const unsigned short*)&v;
        #pragma unroll
        for (int j = 0; j < 8; ++j) {
            _Float16 hv = (_Float16)bf2f(pv[j]);
            dst[j] = *(unsigned short*)&hv;
        }
    }
    __syncthreads();
    unsigned short* out = vtg + (size_t)bh * DH * SEQ + s0;
    #pragma unroll
    for (int i = 0; i < 16; ++i) {
        int idx = t + i*256;
        int d = idx >> 6, s = idx & 63;
        out[(size_t)d * SEQ + s] = T[s*TP + d];
    }
}

// ---------------- stage 2: transposed flash attention, barrier-free K-loop ----------------
// Pl (K-loop P^T buffer) and Os (epilogue O^T stash) now share one LDS region
// (union + end barrier): 37.9 KB total -> 4 blocks/CU instead of 2.
#define PPAD 40   // P^T row pitch (shorts)
#define OPAD 72   // O^T stash row pitch (shorts)
__global__ __launch_bounds__(256, 4) void k_attn(
    const unsigned short* __restrict__ qkv, // bf16 (Q pre-scaled by 0.125*log2e)
    const unsigned short* __restrict__ vtg, // f16 V^T [bh][d][s]
    float* __restrict__ out)
{
    __shared__ __align__(16) unsigned short PO[4*64*OPAD];  // 36 KB union: Pl (loop) / Os (epilogue)
    __shared__ float Lp[4*64];

    const int t = threadIdx.x;
    const int wave = t >> 6, lane = t & 63, quad = lane >> 4, l15 = lane & 15;
    const int bh = blockIdx.y, b = bh >> 4, h = bh & 15;
    const int m0 = blockIdx.x * 64;
    const unsigned short* base  = qkv + (size_t)(b*SEQ)*NQKV + h*(3*DH);
    const unsigned short* kbase = base + DH;
    const unsigned short* vbase = vtg + (size_t)bh * DH * SEQ;

    // Q B-frags: B[k=d][n=q], n=l15, k=quad*8+j (+kc*32). All 64 q-rows per wave.
    bf16x8 qb[4][2];
    #pragma unroll
    for (int tq = 0; tq < 4; ++tq) {
        const unsigned short* qrow = base + (size_t)(m0 + tq*16 + l15) * NQKV;
        qb[tq][0] = *(const bf16x8*)(qrow + quad*8);
        qb[tq][1] = *(const bf16x8*)(qrow + 32 + quad*8);
    }

    f32x4 o[4][4] = {};            // O^T tiles [td][tq]: row=d, col=q
    float lp[4] = {0.f, 0.f, 0.f, 0.f};
    unsigned short* pw = &PO[wave*64*PPAD];

    // double-buffered K/V fragments (direct global loads, L2-resident)
    bf16x8 kf[2][2][2];
    f16x8  vf[2][4];
    {
        int key0 = wave*32;
        #pragma unroll
        for (int tk = 0; tk < 2; ++tk) {
            const unsigned short* kr = kbase + (size_t)(key0 + tk*16 + l15)*NQKV;
            kf[0][tk][0] = *(const bf16x8*)(kr + quad*8);
            kf[0][tk][1] = *(const bf16x8*)(kr + 32 + quad*8);
        }
        #pragma unroll
        for (int td = 0; td < 4; ++td)
            vf[0][td] = *(const f16x8*)(vbase + (size_t)(td*16 + l15)*SEQ + key0 + quad*8);
    }

    #pragma unroll 2
    for (int it = 0; it < 16; ++it) {
        const int cur = it & 1, nxt = cur ^ 1;
        if (it < 15) {  // prefetch next 32-key slice
            int key0 = (it+1)*128 + wave*32;
            #pragma unroll
            for (int tk = 0; tk < 2; ++tk) {
                const unsigned short* kr = kbase + (size_t)(key0 + tk*16 + l15)*NQKV;
                kf[nxt][tk][0] = *(const bf16x8*)(kr + quad*8);
                kf[nxt][tk][1] = *(const bf16x8*)(kr + 32 + quad*8);
            }
            #pragma unroll
            for (int td = 0; td < 4; ++td)
                vf[nxt][td] = *(const f16x8*)(vbase + (size_t)(td*16 + l15)*SEQ + key0 + quad*8);
        }
        // S^T tiles: C'[key][q]: row=key_local=tk*16+quad*4+r, col=q=tq*16+l15
        #pragma unroll
        for (int tk = 0; tk < 2; ++tk) {
            #pragma unroll
            for (int tq = 0; tq < 4; ++tq) {
                f32x4 a = {};
                a = __builtin_amdgcn_mfma_f32_16x16x32_bf16(kf[cur][tk][0], qb[tq][0], a, 0, 0, 0);
                a = __builtin_amdgcn_mfma_f32_16x16x32_bf16(kf[cur][tk][1], qb[tq][1], a, 0, 0, 0);
                float p0 = exp2f(a[0]), p1 = exp2f(a[1]);   // scale pre-folded into Q
                float p2 = exp2f(a[2]), p3 = exp2f(a[3]);
                lp[tq] += (p0 + p1) + (p2 + p3);
                uint2 u; u.x = pkh(p0, p1); u.y = pkh(p2, p3);
                *(uint2*)(&pw[(tq*16 + l15)*PPAD + tk*16 + quad*4]) = u;
            }
        }
        // O^T += V^T · P^T  (A=V^T m=d; B=P^T n=q, k=key=quad*8+j)
        f16x8 pb[4];
        #pragma unroll
        for (int tq = 0; tq < 4; ++tq)
            pb[tq] = *(const f16x8*)(&pw[(tq*16 + l15)*PPAD + quad*8]);
        #pragma unroll
        for (int td = 0; td < 4; ++td)
            #pragma unroll
            for (int tq = 0; tq < 4; ++tq)
                o[td][tq] = __builtin_amdgcn_mfma_f32_16x16x32_f16(vf[cur][td], pb[tq], o[td][tq], 0, 0, 0);
    }

    // l partials (Lp is a separate region — safe before the union barrier)
    #pragma unroll
    for (int tq = 0; tq < 4; ++tq) {
        float s = lp[tq];
        s += __shfl_xor(s, 16);
        s += __shfl_xor(s, 32);
        if (quad == 0) Lp[wave*64 + tq*16 + l15] = s;
    }
    __syncthreads();   // all waves done reading their Pl region before Os overwrites it
    {
        unsigned short* ow = &PO[wave*64*OPAD];
        #pragma unroll
        for (int td = 0; td < 4; ++td)
            #pragma unroll
            for (int tq = 0; tq < 4; ++tq) {
                uint2 u; u.x = pkh(o[td][tq][0], o[td][tq][1]); u.y = pkh(o[td][tq][2], o[td][tq][3]);
                *(uint2*)(&ow[(tq*16 + l15)*OPAD + td*16 + quad*4]) = u;
            }
    }
    __syncthreads();
    float* outb = out + (size_t)(b*SEQ + m0) * (NHEADS*DH) + h*DH;
    #pragma unroll
    for (int i = 0; i < 16; ++i) {
        int idx = t + i*256;
        int q = idx >> 6, d = idx & 63;
        float lt = Lp[q] + Lp[64 + q] + Lp[128 + q] + Lp[192 + q];
        float s = 0.f;
        #pragma unroll
        for (int w2 = 0; w2 < 4; ++w2) {
            _Float16 hv = *(const _Float16*)&PO[(w2*64 + q)*OPAD + d];
            s += (float)hv;
        }
        outb[(size_t)q * (NHEADS*DH) + d] = s / lt;
    }
}

extern "C" void kernel_launch(void* const* d_in, const int* in_sizes, int n_in,
                              void* d_out, int out_size, void* d_ws, size_t ws_size,
                              hipStream_t stream) {
    const float* x    = (const float*)d_in[0];
    const float* W    = (const float*)d_in[1];
    const float* bias = (const float*)d_in[2];
    float* out = (float*)d_out;

    unsigned short* xb  = (unsigned short*)d_ws;                 // 16 MB (reused as vtg after GEMM)
    unsigned short* Wt  = xb  + (size_t)MTOT * D_IN;             // 6 MB
    unsigned short* qkv = Wt  + (size_t)NQKV * D_IN;             // 48 MB
    unsigned short* vtg = xb;                                    // alias: xb dead after GEMM

    hipLaunchKernelGGL(k_convert_x,   dim3(MTOT*D_IN/4/256), dim3(256),    0, stream, x, xb);
    hipLaunchKernelGGL(k_convert_wt,  dim3(NQKV/32, D_IN/32), dim3(32, 8), 0, stream, W, Wt);
    hipLaunchKernelGGL(k_gemm_qkv,    dim3(NQKV/128, MTOT/128), dim3(256), 0, stream, xb, Wt, bias, qkv);
    hipLaunchKernelGGL(k_transpose_v, dim3(SEQ/64, BATCH*NHEADS), dim3(256), 0, stream, qkv, vtg);
    hipLaunchKernelGGL(k_attn,        dim3(SEQ/64, BATCH*NHEADS), dim3(256), 0, stream, qkv, vtg, out);
}

// Round 7
// 297.272 us; speedup vs baseline: 3.0985x; 3.0985x over previous
//
#include <hip/hip_runtime.h>
#include <stdint.h>
#include <math.h>

#define D_IN   1024
#define NQKV   3072
#define NHEADS 16
#define DH     64
#define BATCH  4
#define SEQ    2048
#define MTOT   (BATCH*SEQ)   // 8192

typedef __bf16    bf16x8 __attribute__((ext_vector_type(8)));
typedef _Float16  f16x8  __attribute__((ext_vector_type(8)));
typedef float     f32x4  __attribute__((ext_vector_type(4)));

typedef __attribute__((address_space(3))) unsigned short       lds_us;
typedef __attribute__((address_space(1))) const unsigned short glb_us;

__device__ __forceinline__ unsigned short f2bf(float f) {
    union { float f; uint32_t u; } c; c.f = f;
    uint32_t u = c.u;
    uint32_t r = u + 0x7fffu + ((u >> 16) & 1u);  // RNE
    return (unsigned short)(r >> 16);
}
__device__ __forceinline__ float bf2f(unsigned short b) {
    union { uint32_t u; float f; } c; c.u = ((uint32_t)b) << 16;
    return c.f;
}
__device__ __forceinline__ uint32_t pkh(float a, float b) {
    auto h = __builtin_amdgcn_cvt_pkrtz(a, b);   // __fp16 ext_vector(2)
    uint32_t u;
    __builtin_memcpy(&u, &h, 4);
    return u;
}

// ---------------- stage 0a: x fp32 -> bf16 ----------------
__global__ void k_convert_x(const float* __restrict__ x, unsigned short* __restrict__ xb) {
    int i = blockIdx.x * 256 + threadIdx.x;
    float4 v = ((const float4*)x)[i];
    ushort4 o;
    o.x = f2bf(v.x); o.y = f2bf(v.y); o.z = f2bf(v.z); o.w = f2bf(v.w);
    ((ushort4*)xb)[i] = o;
}

// ---------------- stage 0b: W fp32 [K][N] -> Wt bf16 [N][K] ----------------
__global__ void k_convert_wt(const float* __restrict__ W, unsigned short* __restrict__ Wt) {
    __shared__ float tile[32][33];
    int tx = threadIdx.x, ty = threadIdx.y;
    int n0 = blockIdx.x * 32, k0 = blockIdx.y * 32;
    #pragma unroll
    for (int i = 0; i < 4; ++i) {
        int k = k0 + ty + i*8;
        tile[ty + i*8][tx] = W[(size_t)k * NQKV + n0 + tx];
    }
    __syncthreads();
    #pragma unroll
    for (int i = 0; i < 4; ++i) {
        int n = n0 + ty + i*8;
        Wt[(size_t)n * D_IN + k0 + tx] = f2bf(tile[tx][ty + i*8]);
    }
}

// ---------------- stage 1: QKV = x @ W + b, m97-style global_load_lds GEMM ----------------
// 128x128 tile, BK=32, unpadded LDS [128][32] (2-way bank alias = free), DMA staging.
// Q columns (col%192 < 64) pre-scaled by 0.125*log2e so k_attn's exp2 needs no mul.
__global__ __launch_bounds__(256) void k_gemm_qkv(
    const unsigned short* __restrict__ A,   // [8192][1024] bf16
    const unsigned short* __restrict__ Bt,  // [3072][1024] bf16
    const float* __restrict__ bias,         // [3072]
    unsigned short* __restrict__ C)         // [8192][3072] bf16
{
    __shared__ __align__(16) unsigned short As[128*32];
    __shared__ __align__(16) unsigned short Bs[128*32];
    const int t = threadIdx.x;
    const int wave = t >> 6, lane = t & 63, quad = lane >> 4, l15 = lane & 15;
    const int wm = wave >> 1, wn = wave & 1;
    const int m0 = blockIdx.y * 128, n0 = blockIdx.x * 128;
    const int crow = lane >> 2;          // row within 16-row chunk
    const int ccol = (lane & 3) << 3;    // short col within row

    f32x4 acc[4][4] = {};
    lds_us* As3 = (lds_us*)As;
    lds_us* Bs3 = (lds_us*)Bs;

    for (int k0 = 0; k0 < D_IN; k0 += 32) {
        // stage A,B tiles: each wave DMAs 2 chunks of 16 rows each (1024 B per instr)
        #pragma unroll
        for (int j = 0; j < 2; ++j) {
            int chunk = wave*2 + j;
            const unsigned short* ga = A  + (size_t)(m0 + chunk*16 + crow)*D_IN + k0 + ccol;
            const unsigned short* gb = Bt + (size_t)(n0 + chunk*16 + crow)*D_IN + k0 + ccol;
            __builtin_amdgcn_global_load_lds((glb_us*)ga, As3 + chunk*512, 16, 0, 0);
            __builtin_amdgcn_global_load_lds((glb_us*)gb, Bs3 + chunk*512, 16, 0, 0);
        }
        __syncthreads();   // drains vmcnt -> staging visible
        bf16x8 a[4], b[4];
        #pragma unroll
        for (int tm = 0; tm < 4; ++tm)
            a[tm] = *(const bf16x8*)(&As[(wm*64 + tm*16 + l15)*32 + quad*8]);
        #pragma unroll
        for (int tn = 0; tn < 4; ++tn)
            b[tn] = *(const bf16x8*)(&Bs[(wn*64 + tn*16 + l15)*32 + quad*8]);
        #pragma unroll
        for (int tm = 0; tm < 4; ++tm)
            #pragma unroll
            for (int tn = 0; tn < 4; ++tn)
                acc[tm][tn] = __builtin_amdgcn_mfma_f32_16x16x32_bf16(a[tm], b[tn], acc[tm][tn], 0, 0, 0);
        __syncthreads();   // protect LDS before next iteration's DMA overwrite
    }
    const float qs = 0.125f * 1.44269504089f;
    #pragma unroll
    for (int tn = 0; tn < 4; ++tn) {
        int col = n0 + wn*64 + tn*16 + l15;
        float bv = bias[col];
        float s = ((col % 192) < 64) ? qs : 1.0f;   // pre-scale Q columns
        #pragma unroll
        for (int tm = 0; tm < 4; ++tm) {
            #pragma unroll
            for (int r = 0; r < 4; ++r) {
                int row = m0 + wm*64 + tm*16 + quad*4 + r;
                C[(size_t)row*NQKV + col] = f2bf((acc[tm][tn][r] + bv) * s);
            }
        }
    }
}

// ---------------- stage 1b: V (bf16, strided in qkv) -> Vt f16 [bh][d][s] ----------------
#define TP 66
__global__ __launch_bounds__(256) void k_transpose_v(
    const unsigned short* __restrict__ qkv,
    unsigned short* __restrict__ vtg)       // f16 bits
{
    __shared__ unsigned short T[64*TP];     // [s][d] as f16
    const int t = threadIdx.x;
    const int bh = blockIdx.y, b = bh >> 4, h = bh & 15;
    const int s0 = blockIdx.x * 64;
    const unsigned short* src = qkv + (size_t)(b*SEQ + s0)*NQKV + h*(3*DH) + 2*DH;
    #pragma unroll
    for (int i = 0; i < 2; ++i) {
        int idx = t + i*256;
        int s = idx >> 3, c = (idx & 7) << 3;
        uint4 v = *(const uint4*)(src + (size_t)s*NQKV + c);   // 16 B = 8 bf16
        unsigned short* dst = &T[s*TP + c];
        const unsigned short* pv = (const unsigned short*)&v;
        #pragma unroll
        for (int j = 0; j < 8; ++j) {
            _Float16 hv = (_Float16)bf2f(pv[j]);
            dst[j] = *(unsigned short*)&hv;
        }
    }
    __syncthreads();
    unsigned short* out = vtg + (size_t)bh * DH * SEQ + s0;
    #pragma unroll
    for (int i = 0; i < 16; ++i) {
        int idx = t + i*256;
        int d = idx >> 6, s = idx & 63;
        out[(size_t)d * SEQ + s] = T[s*TP + d];
    }
}

// ---------------- stage 2: transposed flash attention, barrier-free K-loop ----------------
// LDS union (Pl loop / Os epilogue) keeps LDS at 37.9 KB -> 4 blocks/CU by LDS.
// launch_bounds (256,2): do NOT force 4 waves/EU — that caps VGPR at 64 and
// spills the K/V/Q fragment working set to scratch (R6: 2 GB scratch traffic,
// 720 us). With natural allocation (~124 VGPR) occupancy is still 4 blocks/CU.
#define PPAD 40   // P^T row pitch (shorts)
#define OPAD 72   // O^T stash row pitch (shorts)
__global__ __launch_bounds__(256, 2) void k_attn(
    const unsigned short* __restrict__ qkv, // bf16 (Q pre-scaled by 0.125*log2e)
    const unsigned short* __restrict__ vtg, // f16 V^T [bh][d][s]
    float* __restrict__ out)
{
    __shared__ __align__(16) unsigned short PO[4*64*OPAD];  // 36 KB union: Pl (loop) / Os (epilogue)
    __shared__ float Lp[4*64];

    const int t = threadIdx.x;
    const int wave = t >> 6, lane = t & 63, quad = lane >> 4, l15 = lane & 15;
    const int bh = blockIdx.y, b = bh >> 4, h = bh & 15;
    const int m0 = blockIdx.x * 64;
    const unsigned short* base  = qkv + (size_t)(b*SEQ)*NQKV + h*(3*DH);
    const unsigned short* kbase = base + DH;
    const unsigned short* vbase = vtg + (size_t)bh * DH * SEQ;

    // Q B-frags: B[k=d][n=q], n=l15, k=quad*8+j (+kc*32). All 64 q-rows per wave.
    bf16x8 qb[4][2];
    #pragma unroll
    for (int tq = 0; tq < 4; ++tq) {
        const unsigned short* qrow = base + (size_t)(m0 + tq*16 + l15) * NQKV;
        qb[tq][0] = *(const bf16x8*)(qrow + quad*8);
        qb[tq][1] = *(const bf16x8*)(qrow + 32 + quad*8);
    }

    f32x4 o[4][4] = {};            // O^T tiles [td][tq]: row=d, col=q
    float lp[4] = {0.f, 0.f, 0.f, 0.f};
    unsigned short* pw = &PO[wave*64*PPAD];

    // double-buffered K/V fragments (direct global loads, L2-resident)
    bf16x8 kf[2][2][2];
    f16x8  vf[2][4];
    {
        int key0 = wave*32;
        #pragma unroll
        for (int tk = 0; tk < 2; ++tk) {
            const unsigned short* kr = kbase + (size_t)(key0 + tk*16 + l15)*NQKV;
            kf[0][tk][0] = *(const bf16x8*)(kr + quad*8);
            kf[0][tk][1] = *(const bf16x8*)(kr + 32 + quad*8);
        }
        #pragma unroll
        for (int td = 0; td < 4; ++td)
            vf[0][td] = *(const f16x8*)(vbase + (size_t)(td*16 + l15)*SEQ + key0 + quad*8);
    }

    #pragma unroll 2
    for (int it = 0; it < 16; ++it) {
        const int cur = it & 1, nxt = cur ^ 1;
        if (it < 15) {  // prefetch next 32-key slice
            int key0 = (it+1)*128 + wave*32;
            #pragma unroll
            for (int tk = 0; tk < 2; ++tk) {
                const unsigned short* kr = kbase + (size_t)(key0 + tk*16 + l15)*NQKV;
                kf[nxt][tk][0] = *(const bf16x8*)(kr + quad*8);
                kf[nxt][tk][1] = *(const bf16x8*)(kr + 32 + quad*8);
            }
            #pragma unroll
            for (int td = 0; td < 4; ++td)
                vf[nxt][td] = *(const f16x8*)(vbase + (size_t)(td*16 + l15)*SEQ + key0 + quad*8);
        }
        // S^T tiles: C'[key][q]: row=key_local=tk*16+quad*4+r, col=q=tq*16+l15
        #pragma unroll
        for (int tk = 0; tk < 2; ++tk) {
            #pragma unroll
            for (int tq = 0; tq < 4; ++tq) {
                f32x4 a = {};
                a = __builtin_amdgcn_mfma_f32_16x16x32_bf16(kf[cur][tk][0], qb[tq][0], a, 0, 0, 0);
                a = __builtin_amdgcn_mfma_f32_16x16x32_bf16(kf[cur][tk][1], qb[tq][1], a, 0, 0, 0);
                float p0 = exp2f(a[0]), p1 = exp2f(a[1]);   // scale pre-folded into Q
                float p2 = exp2f(a[2]), p3 = exp2f(a[3]);
                lp[tq] += (p0 + p1) + (p2 + p3);
                uint2 u; u.x = pkh(p0, p1); u.y = pkh(p2, p3);
                *(uint2*)(&pw[(tq*16 + l15)*PPAD + tk*16 + quad*4]) = u;
            }
        }
        // O^T += V^T · P^T  (A=V^T m=d; B=P^T n=q, k=key=quad*8+j)
        f16x8 pb[4];
        #pragma unroll
        for (int tq = 0; tq < 4; ++tq)
            pb[tq] = *(const f16x8*)(&pw[(tq*16 + l15)*PPAD + quad*8]);
        #pragma unroll
        for (int td = 0; td < 4; ++td)
            #pragma unroll
            for (int tq = 0; tq < 4; ++tq)
                o[td][tq] = __builtin_amdgcn_mfma_f32_16x16x32_f16(vf[cur][td], pb[tq], o[td][tq], 0, 0, 0);
    }

    // l partials (Lp is a separate region — safe before the union barrier)
    #pragma unroll
    for (int tq = 0; tq < 4; ++tq) {
        float s = lp[tq];
        s += __shfl_xor(s, 16);
        s += __shfl_xor(s, 32);
        if (quad == 0) Lp[wave*64 + tq*16 + l15] = s;
    }
    __syncthreads();   // all waves done reading their Pl region before Os overwrites it
    {
        unsigned short* ow = &PO[wave*64*OPAD];
        #pragma unroll
        for (int td = 0; td < 4; ++td)
            #pragma unroll
            for (int tq = 0; tq < 4; ++tq) {
                uint2 u; u.x = pkh(o[td][tq][0], o[td][tq][1]); u.y = pkh(o[td][tq][2], o[td][tq][3]);
                *(uint2*)(&ow[(tq*16 + l15)*OPAD + td*16 + quad*4]) = u;
            }
    }
    __syncthreads();
    float* outb = out + (size_t)(b*SEQ + m0) * (NHEADS*DH) + h*DH;
    #pragma unroll
    for (int i = 0; i < 16; ++i) {
        int idx = t + i*256;
        int q = idx >> 6, d = idx & 63;
        float lt = Lp[q] + Lp[64 + q] + Lp[128 + q] + Lp[192 + q];
        float s = 0.f;
        #pragma unroll
        for (int w2 = 0; w2 < 4; ++w2) {
            _Float16 hv = *(const _Float16*)&PO[(w2*64 + q)*OPAD + d];
            s += (float)hv;
        }
        outb[(size_t)q * (NHEADS*DH) + d] = s / lt;
    }
}

extern "C" void kernel_launch(void* const* d_in, const int* in_sizes, int n_in,
                              void* d_out, int out_size, void* d_ws, size_t ws_size,
                              hipStream_t stream) {
    const float* x    = (const float*)d_in[0];
    const float* W    = (const float*)d_in[1];
    const float* bias = (const float*)d_in[2];
    float* out = (float*)d_out;

    unsigned short* xb  = (unsigned short*)d_ws;                 // 16 MB (reused as vtg after GEMM)
    unsigned short* Wt  = xb  + (size_t)MTOT * D_IN;             // 6 MB
    unsigned short* qkv = Wt  + (size_t)NQKV * D_IN;             // 48 MB
    unsigned short* vtg = xb;                                    // alias: xb dead after GEMM

    hipLaunchKernelGGL(k_convert_x,   dim3(MTOT*D_IN/4/256), dim3(256),    0, stream, x, xb);
    hipLaunchKernelGGL(k_convert_wt,  dim3(NQKV/32, D_IN/32), dim3(32, 8), 0, stream, W, Wt);
    hipLaunchKernelGGL(k_gemm_qkv,    dim3(NQKV/128, MTOT/128), dim3(256), 0, stream, xb, Wt, bias, qkv);
    hipLaunchKernelGGL(k_transpose_v, dim3(SEQ/64, BATCH*NHEADS), dim3(256), 0, stream, qkv, vtg);
    hipLaunchKernelGGL(k_attn,        dim3(SEQ/64, BATCH*NHEADS), dim3(256), 0, stream, qkv, vtg, out);
}